// Round 1
// baseline (113.572 us; speedup 1.0000x reference)
//
#include <hip/hip_runtime.h>
#include <hip/hip_cooperative_groups.h>

namespace cg = cooperative_groups;

// out[d] = sum_{e: dst[e]==d} x[src[e]]   (N=100k, E=1.6M, D=32 f32)
//
// Round-10/11 lessons: each dispatch in the timed graph costs a ~43us slot
// (a 4-byte memset measured 43us; removing one dispatch saved exactly that).
// Round 12: fuse scatter+gather into ONE cooperative kernel with grid.sync()
// -> 1-kernel graph. 512 blocks x 512 thr, 53.2KB dyn LDS = 2 blocks/CU
// co-resident (512 total). Phase 2 distributes 782 buckets via atomic ticket;
// phase-2 LDS (37.9KB) overlays the phase-1 stage buffer.

#define D_FEAT 32
#define BKT_SHIFT 7
#define BKT_NODES 128
#define CAPSH 4               // 16 slots per sub-bin (64B = 1 line)
#define CAP (1 << CAPSH)
#define ECAP 4096             // packed entries per gather flush
#define OVFB 512              // overflow pairs per scatter block
#define NSUB 512              // fused grid size / edge chunks
typedef unsigned int u32;

// ==================== fused cooperative kernel ====================

__global__ void __launch_bounds__(512, 4)
k_fused(const float* __restrict__ x, const int* __restrict__ src,
        const int* __restrict__ dst, u32* __restrict__ cnt,
        u32* __restrict__ bin, u32* __restrict__ ovfb, u32* __restrict__ ovfn,
        u32* __restrict__ ticket, float* __restrict__ out,
        int n_edges, int n_nodes, int nb, int chunk) {
    extern __shared__ u32 smem[];
    __shared__ u32 s_ovf_n;
    __shared__ u32 s_wsum[8];
    __shared__ u32 s_bkt;
    const int nsub = NSUB;
    const int blk = blockIdx.x;
    const int t = threadIdx.x;
    const int lane = t & 63, wid = t >> 6;

    // ---------------- phase 1: scatter (== k_scatter5) ----------------
    {
        u32* s_stage = smem;                          // nb*CAP words
        u32* s_cur   = smem + ((size_t)nb << CAPSH);  // nb words
        for (int i = t; i < nb; i += 512) s_cur[i] = 0u;
        if (t == 0) s_ovf_n = 0u;
        if (blk == 0 && t == 0) *ticket = 0u;   // visible after grid.sync
        __syncthreads();
        int beg = blk * chunk, end = min(beg + chunk, n_edges);
        for (int e = beg + t; e < end; e += 512) {
            u32 d = (u32)dst[e];
            u32 bkt = d >> BKT_SHIFT;
            u32 pos = atomicAdd(&s_cur[bkt], 1u);        // LDS-only RMW
            u32 packed = (u32)src[e] | ((d & (BKT_NODES - 1)) << 17);
            if (pos < (u32)CAP) {
                s_stage[(bkt << CAPSH) + pos] = packed;
            } else {
                u32 g = atomicAdd(&s_ovf_n, 1u);         // ~never taken
                if (g < (u32)OVFB) {
                    ovfb[((size_t)blk * OVFB + g) * 2]     = packed;
                    ovfb[((size_t)blk * OVFB + g) * 2 + 1] = bkt;
                }
            }
        }
        __syncthreads();
        // gated bucket-major flush: bin[b][blk][slot]
        const uint4* sq = (const uint4*)s_stage;
        uint4* gq = (uint4*)bin;
        int nquads = nb << (CAPSH - 2);
        for (int i = t; i < nquads; i += 512) {
            int bkt = i >> (CAPSH - 2);
            int k4  = i & ((1 << (CAPSH - 2)) - 1);
            u32 cn = min(s_cur[bkt], (u32)CAP);
            if ((u32)(k4 << 2) < cn)
                gq[(((size_t)bkt * nsub + blk) << (CAPSH - 2)) + k4] = sq[i];
        }
        u32* row = cnt + (size_t)blk * nb;
        for (int i = t; i < nb; i += 512) row[i] = min(s_cur[i], (u32)CAP);
        if (t == 0) ovfn[blk] = min(s_ovf_n, (u32)OVFB);
    }

    __threadfence();             // release phase-1 stores (cross-XCD)
    cg::this_grid().sync();
    __threadfence();             // acquire side: discard stale lines

    // ---------------- phase 2: gather (== k_gather5, ticket-driven) ----
    u32* g_cnt  = smem;                     // 512
    u32* g_base = smem + 512;               // 513
    u32* g_ent  = smem + 1025;              // ECAP
    u32* g_srt  = g_ent + ECAP;             // ECAP
    u32* g_off  = g_srt + ECAP;             // BKT_NODES+1
    u32* g_cur  = g_off + (BKT_NODES + 1);  // BKT_NODES   (total 9474 w < 13294 w)

    const float4* x4 = (const float4*)x;
    const uint4* bin4 = (const uint4*)bin;
    const int q = t & 7;
    const int n0 = t >> 3;

    u32 mo = (t < nsub) ? ovfn[t] : 0u;                 // hoisted once
    const int has_ovf = __syncthreads_or(mo != 0u);

    for (;;) {
        __syncthreads();                  // protect smem reuse + s_bkt
        if (t == 0) s_bkt = atomicAdd(ticket, 1u);
        __syncthreads();
        const int b = (int)s_bkt;
        if (b >= nb) break;
        const int node0 = b << BKT_SHIFT;
        float4 a0 = make_float4(0.f, 0.f, 0.f, 0.f);
        float4 a1 = make_float4(0.f, 0.f, 0.f, 0.f);

        // sub-bin counts + exclusive scan (wave shfl + cross-wave fix)
        u32 c = min(cnt[(size_t)t * nb + b], (u32)CAP);
        g_cnt[t] = c;
        u32 s = c;
        #pragma unroll
        for (int off = 1; off < 64; off <<= 1) {
            u32 y = __shfl_up(s, off, 64);
            if (lane >= off) s += y;
        }
        if (lane == 63) s_wsum[wid] = s;
        __syncthreads();
        if (t == 0) {
            u32 run = 0u;
            #pragma unroll
            for (int w = 0; w < 8; ++w) { u32 v = s_wsum[w]; s_wsum[w] = run; run += v; }
        }
        __syncthreads();
        u32 incl = s + s_wsum[wid];
        g_base[t] = incl - c;              // exclusive
        if (t == 511) g_base[512] = incl;
        __syncthreads();

        int subA = 0;
        u32 baseA = 0u;
        while (subA < nsub) {
            // largest subB with base[subB]-baseA <= ECAP
            int lo = subA + 1, hi = nsub;
            while (lo < hi) {
                int mid = (lo + hi + 1) >> 1;
                if (g_base[mid] - baseA <= (u32)ECAP) lo = mid; else hi = mid - 1;
            }
            int subB = lo;
            int m = (int)(g_base[subB] - baseA);

            // pack sub-bins [subA,subB): sequential gated uint4 stream
            {
                int quads = (subB - subA) << (CAPSH - 2);
                size_t qbase = ((size_t)b * nsub + subA) << (CAPSH - 2);
                for (int i = t; i < quads; i += 512) {
                    int sub = subA + (i >> (CAPSH - 2));
                    int slot0 = (i & ((1 << (CAPSH - 2)) - 1)) << 2;
                    u32 cn = g_cnt[sub];
                    if ((u32)slot0 < cn) {
                        uint4 v = bin4[qbase + i];
                        u32 base = (g_base[sub] - baseA) + slot0;
                        g_ent[base] = v.x;
                        if ((u32)(slot0 + 1) < cn) g_ent[base + 1] = v.y;
                        if ((u32)(slot0 + 2) < cn) g_ent[base + 2] = v.z;
                        if ((u32)(slot0 + 3) < cn) g_ent[base + 3] = v.w;
                    }
                }
            }
            if (t < BKT_NODES) g_cur[t] = 0u;
            __syncthreads();

            // count by dlocal
            for (int i = t; i < m; i += 512) atomicAdd(&g_cur[g_ent[i] >> 17], 1u);
            __syncthreads();

            // 128-entry exclusive scan by wave 0 (2 entries/lane, shfl)
            if (wid == 0) {
                u32 v0 = g_cur[2 * lane], v1 = g_cur[2 * lane + 1];
                u32 ps = v0 + v1;
                #pragma unroll
                for (int off = 1; off < 64; off <<= 1) {
                    u32 y = __shfl_up(ps, off, 64);
                    if (lane >= off) ps += y;
                }
                u32 ex = ps - (v0 + v1);
                g_off[2 * lane] = ex;          g_cur[2 * lane] = ex;
                g_off[2 * lane + 1] = ex + v0; g_cur[2 * lane + 1] = ex + v0;
                if (lane == 63) g_off[BKT_NODES] = ps;
            }
            __syncthreads();

            // rank into g_srt
            for (int i = t; i < m; i += 512) {
                u32 p = g_ent[i];
                u32 pos = atomicAdd(&g_cur[p >> 17], 1u);
                g_srt[pos] = p & 0x1FFFFu;
            }
            __syncthreads();

            // accumulate: 8 lanes share one 128B x-row; 4-way unroll for MLP
            {
                u32 j = g_off[n0], j1 = g_off[n0 + 1];
                for (; j + 3 < j1; j += 4) {
                    float4 xa = x4[(size_t)g_srt[j] * 8 + q];
                    float4 xb = x4[(size_t)g_srt[j + 1] * 8 + q];
                    float4 xc = x4[(size_t)g_srt[j + 2] * 8 + q];
                    float4 xd = x4[(size_t)g_srt[j + 3] * 8 + q];
                    a0.x += xa.x + xb.x + xc.x + xd.x;
                    a0.y += xa.y + xb.y + xc.y + xd.y;
                    a0.z += xa.z + xb.z + xc.z + xd.z;
                    a0.w += xa.w + xb.w + xc.w + xd.w;
                }
                for (; j < j1; ++j) {
                    float4 xa = x4[(size_t)g_srt[j] * 8 + q];
                    a0.x += xa.x; a0.y += xa.y; a0.z += xa.z; a0.w += xa.w;
                }
                j = g_off[n0 + 64]; j1 = g_off[n0 + 65];
                for (; j + 3 < j1; j += 4) {
                    float4 xa = x4[(size_t)g_srt[j] * 8 + q];
                    float4 xb = x4[(size_t)g_srt[j + 1] * 8 + q];
                    float4 xc = x4[(size_t)g_srt[j + 2] * 8 + q];
                    float4 xd = x4[(size_t)g_srt[j + 3] * 8 + q];
                    a1.x += xa.x + xb.x + xc.x + xd.x;
                    a1.y += xa.y + xb.y + xc.y + xd.y;
                    a1.z += xa.z + xb.z + xc.z + xd.z;
                    a1.w += xa.w + xb.w + xc.w + xd.w;
                }
                for (; j < j1; ++j) {
                    float4 xa = x4[(size_t)g_srt[j] * 8 + q];
                    a1.x += xa.x; a1.y += xa.y; a1.z += xa.z; a1.w += xa.w;
                }
            }
            __syncthreads();
            subA = subB;
            baseA = g_base[subB];
        }

        // replay per-block overflow lists (normally all empty)
        if (has_ovf) {
            for (int sub = 0; sub < nsub; ++sub) {
                u32 n = ovfn[sub];
                for (u32 i = 0; i < n; ++i) {
                    u32 ob = ovfb[((size_t)sub * OVFB + i) * 2 + 1];
                    if (ob == (u32)b) {
                        u32 p = ovfb[((size_t)sub * OVFB + i) * 2];
                        u32 dl = p >> 17;
                        if (dl == (u32)n0 || dl == (u32)(n0 + 64)) {
                            float4 xv = x4[(size_t)(p & 0x1FFFFu) * 8 + q];
                            if (dl == (u32)n0) { a0.x += xv.x; a0.y += xv.y; a0.z += xv.z; a0.w += xv.w; }
                            else               { a1.x += xv.x; a1.y += xv.y; a1.z += xv.z; a1.w += xv.w; }
                        }
                    }
                }
            }
        }

        float4* o4 = (float4*)out;
        if (node0 + n0 < n_nodes)      o4[(size_t)node0 * 8 + t] = a0;
        if (node0 + n0 + 64 < n_nodes) o4[(size_t)node0 * 8 + 512 + t] = a1;
    }
}

// ==================== 2-kernel fallback (round-11 proven path) ====================

__global__ void __launch_bounds__(512)
k_scatter5(const int* __restrict__ src, const int* __restrict__ dst,
           u32* __restrict__ cnt, u32* __restrict__ bin,
           u32* __restrict__ ovfb, u32* __restrict__ ovfn,
           int n_edges, int nb, int nsub, int chunk) {
    extern __shared__ u32 smem[];
    u32* s_stage = smem;
    u32* s_cur   = smem + ((size_t)nb << CAPSH);
    __shared__ u32 s_ovf_n;
    int blk = blockIdx.x, t = threadIdx.x;
    for (int i = t; i < nb; i += 512) s_cur[i] = 0u;
    if (t == 0) s_ovf_n = 0u;
    __syncthreads();
    int beg = blk * chunk, end = min(beg + chunk, n_edges);
    for (int e = beg + t; e < end; e += 512) {
        u32 d = (u32)dst[e];
        u32 b = d >> BKT_SHIFT;
        u32 pos = atomicAdd(&s_cur[b], 1u);
        u32 packed = (u32)src[e] | ((d & (BKT_NODES - 1)) << 17);
        if (pos < (u32)CAP) {
            s_stage[(b << CAPSH) + pos] = packed;
        } else {
            u32 g = atomicAdd(&s_ovf_n, 1u);
            if (g < (u32)OVFB) {
                ovfb[((size_t)blk * OVFB + g) * 2]     = packed;
                ovfb[((size_t)blk * OVFB + g) * 2 + 1] = (u32)b;
            }
        }
    }
    __syncthreads();
    {
        const uint4* sq = (const uint4*)s_stage;
        uint4* gq = (uint4*)bin;
        int nquads = nb << (CAPSH - 2);
        for (int i = t; i < nquads; i += 512) {
            int b  = i >> (CAPSH - 2);
            int k4 = i & ((1 << (CAPSH - 2)) - 1);
            u32 cn = min(s_cur[b], (u32)CAP);
            if ((u32)(k4 << 2) < cn)
                gq[(((size_t)b * nsub + blk) << (CAPSH - 2)) + k4] = sq[i];
        }
    }
    u32* row = cnt + (size_t)blk * nb;
    for (int i = t; i < nb; i += 512) row[i] = min(s_cur[i], (u32)CAP);
    if (t == 0) ovfn[blk] = min(s_ovf_n, (u32)OVFB);
}

__global__ void __launch_bounds__(512)
k_gather5(const float* __restrict__ x, const u32* __restrict__ cnt,
          const u32* __restrict__ bin, const u32* __restrict__ ovfb,
          const u32* __restrict__ ovfn, float* __restrict__ out,
          int n_nodes, int nb, int nsub) {
    __shared__ u32 s_cnt[512];
    __shared__ u32 s_base[513];
    __shared__ u32 s_wsum[8];
    __shared__ u32 s_ent[ECAP];
    __shared__ u32 s_srt[ECAP];
    __shared__ u32 s_off[BKT_NODES + 1];
    __shared__ u32 s_cur[BKT_NODES];
    __shared__ u32 s_has;
    int b = blockIdx.x, t = threadIdx.x;
    int lane = t & 63, wid = t >> 6;
    int node0 = b * BKT_NODES;
    const float4* x4 = (const float4*)x;
    const uint4* bin4 = (const uint4*)bin;
    int q = t & 7;
    int n0 = t >> 3;
    float4 a0 = make_float4(0.f, 0.f, 0.f, 0.f);
    float4 a1 = make_float4(0.f, 0.f, 0.f, 0.f);

    u32 c = (t < nsub) ? min(cnt[(size_t)t * nb + b], (u32)CAP) : 0u;
    u32 myovf = (t < nsub) ? ovfn[t] : 0u;
    s_cnt[t] = c;
    if (t == 0) s_has = 0u;
    u32 s = c;
    #pragma unroll
    for (int off = 1; off < 64; off <<= 1) {
        u32 y = __shfl_up(s, off, 64);
        if (lane >= off) s += y;
    }
    if (lane == 63) s_wsum[wid] = s;
    __syncthreads();
    if (t == 0) {
        u32 run = 0u;
        #pragma unroll
        for (int w = 0; w < 8; ++w) { u32 v = s_wsum[w]; s_wsum[w] = run; run += v; }
    }
    if (myovf) atomicOr(&s_has, 1u);
    __syncthreads();
    u32 incl = s + s_wsum[wid];
    s_base[t] = incl - c;
    if (t == 511) s_base[512] = incl;
    __syncthreads();

    int subA = 0;
    u32 baseA = 0u;
    while (subA < nsub) {
        int lo = subA + 1, hi = nsub;
        while (lo < hi) {
            int mid = (lo + hi + 1) >> 1;
            if (s_base[mid] - baseA <= (u32)ECAP) lo = mid; else hi = mid - 1;
        }
        int subB = lo;
        int m = (int)(s_base[subB] - baseA);

        {
            int quads = (subB - subA) << (CAPSH - 2);
            size_t qbase = ((size_t)b * nsub + subA) << (CAPSH - 2);
            for (int i = t; i < quads; i += 512) {
                int sub = subA + (i >> (CAPSH - 2));
                int slot0 = (i & ((1 << (CAPSH - 2)) - 1)) << 2;
                u32 cn = s_cnt[sub];
                if ((u32)slot0 < cn) {
                    uint4 v = bin4[qbase + i];
                    u32 base = (s_base[sub] - baseA) + slot0;
                    s_ent[base] = v.x;
                    if ((u32)(slot0 + 1) < cn) s_ent[base + 1] = v.y;
                    if ((u32)(slot0 + 2) < cn) s_ent[base + 2] = v.z;
                    if ((u32)(slot0 + 3) < cn) s_ent[base + 3] = v.w;
                }
            }
        }
        if (t < BKT_NODES) s_cur[t] = 0u;
        __syncthreads();

        for (int i = t; i < m; i += 512) atomicAdd(&s_cur[s_ent[i] >> 17], 1u);
        __syncthreads();

        if (wid == 0) {
            u32 v0 = s_cur[2 * lane], v1 = s_cur[2 * lane + 1];
            u32 ps = v0 + v1;
            #pragma unroll
            for (int off = 1; off < 64; off <<= 1) {
                u32 y = __shfl_up(ps, off, 64);
                if (lane >= off) ps += y;
            }
            u32 ex = ps - (v0 + v1);
            s_off[2 * lane] = ex;     s_cur[2 * lane] = ex;
            s_off[2 * lane + 1] = ex + v0; s_cur[2 * lane + 1] = ex + v0;
            if (lane == 63) s_off[BKT_NODES] = ps;
        }
        __syncthreads();

        for (int i = t; i < m; i += 512) {
            u32 p = s_ent[i];
            u32 pos = atomicAdd(&s_cur[p >> 17], 1u);
            s_srt[pos] = p & 0x1FFFFu;
        }
        __syncthreads();

        {
            u32 j = s_off[n0], j1 = s_off[n0 + 1];
            for (; j + 3 < j1; j += 4) {
                float4 xa = x4[(size_t)s_srt[j] * 8 + q];
                float4 xb = x4[(size_t)s_srt[j + 1] * 8 + q];
                float4 xc = x4[(size_t)s_srt[j + 2] * 8 + q];
                float4 xd = x4[(size_t)s_srt[j + 3] * 8 + q];
                a0.x += xa.x + xb.x + xc.x + xd.x;
                a0.y += xa.y + xb.y + xc.y + xd.y;
                a0.z += xa.z + xb.z + xc.z + xd.z;
                a0.w += xa.w + xb.w + xc.w + xd.w;
            }
            for (; j < j1; ++j) {
                float4 xa = x4[(size_t)s_srt[j] * 8 + q];
                a0.x += xa.x; a0.y += xa.y; a0.z += xa.z; a0.w += xa.w;
            }
            j = s_off[n0 + 64]; j1 = s_off[n0 + 65];
            for (; j + 3 < j1; j += 4) {
                float4 xa = x4[(size_t)s_srt[j] * 8 + q];
                float4 xb = x4[(size_t)s_srt[j + 1] * 8 + q];
                float4 xc = x4[(size_t)s_srt[j + 2] * 8 + q];
                float4 xd = x4[(size_t)s_srt[j + 3] * 8 + q];
                a1.x += xa.x + xb.x + xc.x + xd.x;
                a1.y += xa.y + xb.y + xc.y + xd.y;
                a1.z += xa.z + xb.z + xc.z + xd.z;
                a1.w += xa.w + xb.w + xc.w + xd.w;
            }
            for (; j < j1; ++j) {
                float4 xa = x4[(size_t)s_srt[j] * 8 + q];
                a1.x += xa.x; a1.y += xa.y; a1.z += xa.z; a1.w += xa.w;
            }
        }
        __syncthreads();
        subA = subB;
        baseA = s_base[subB];
    }

    if (s_has) {
        for (int sub = 0; sub < nsub; ++sub) {
            u32 n = ovfn[sub];
            for (u32 i = 0; i < n; ++i) {
                u32 ob = ovfb[((size_t)sub * OVFB + i) * 2 + 1];
                if (ob == (u32)b) {
                    u32 p = ovfb[((size_t)sub * OVFB + i) * 2];
                    u32 dl = p >> 17;
                    if (dl == (u32)n0 || dl == (u32)(n0 + 64)) {
                        float4 xv = x4[(size_t)(p & 0x1FFFFu) * 8 + q];
                        if (dl == (u32)n0) { a0.x += xv.x; a0.y += xv.y; a0.z += xv.z; a0.w += xv.w; }
                        else               { a1.x += xv.x; a1.y += xv.y; a1.z += xv.z; a1.w += xv.w; }
                    }
                }
            }
        }
    }

    float4* o4 = (float4*)out;
    if (node0 + n0 < n_nodes)      o4[(size_t)node0 * 8 + t] = a0;
    if (node0 + n0 + 64 < n_nodes) o4[(size_t)node0 * 8 + 512 + t] = a1;
}

// ---------------- last-resort atomic path ----------------

__global__ void __launch_bounds__(256)
mp_zero_kernel(float* __restrict__ out, int n) {
    int i = blockIdx.x * blockDim.x + threadIdx.x;
    if (i < n) out[i] = 0.0f;
}

__global__ void __launch_bounds__(256)
mp_scatter_kernel(const float* __restrict__ x, const int* __restrict__ src,
                  const int* __restrict__ dst, float* __restrict__ out,
                  int n_edges) {
    int idx = blockIdx.x * blockDim.x + threadIdx.x;
    if (idx >= n_edges * 8) return;
    int e = idx >> 3;
    int c = idx & 7;
    const float4 v = *reinterpret_cast<const float4*>(x + (size_t)src[e] * D_FEAT + c * 4);
    float* o = out + (size_t)dst[e] * D_FEAT + c * 4;
    unsafeAtomicAdd(o + 0, v.x);
    unsafeAtomicAdd(o + 1, v.y);
    unsafeAtomicAdd(o + 2, v.z);
    unsafeAtomicAdd(o + 3, v.w);
}

// ==================== launch ====================

extern "C" void kernel_launch(void* const* d_in, const int* in_sizes, int n_in,
                              void* d_out, int out_size, void* d_ws, size_t ws_size,
                              hipStream_t stream) {
    const float* x = (const float*)d_in[0];
    const int* edge_index = (const int*)d_in[1];
    int n_edges = in_sizes[1] / 2;
    const int* src = edge_index;            // row 0: source j
    const int* dst = edge_index + n_edges;  // row 1: target i
    float* out = (float*)d_out;
    int n_nodes = out_size / D_FEAT;

    int nb = (n_nodes + BKT_NODES - 1) >> BKT_SHIFT;     // 782

    size_t sc_lds = ((size_t)nb * CAP + nb) * sizeof(u32);   // 53.2 KB @ nb=782

    if (n_nodes <= (1 << 17) && sc_lds <= 64 * 1024) {
        // ---- preferred: fused 1-kernel cooperative graph ----
        {
            int nsub = NSUB;
            int chunk = (n_edges + nsub - 1) / nsub;
            size_t need = ((size_t)nsub * nb + 512 + 2 * (size_t)nsub * OVFB
                           + (((size_t)nb * nsub) << CAPSH) + 16) * sizeof(u32);
            if (need <= ws_size) {
                u32* cnt_p  = (u32*)d_ws;
                u32* ovfn_p = cnt_p + (size_t)nsub * nb;
                u32* ovfb_p = ovfn_p + 512;
                u32* bin_p  = ovfb_p + 2 * (size_t)nsub * OVFB;
                u32* tick_p = bin_p + (((size_t)nb * nsub) << CAPSH);

                static int coop_blocks = -1;   // cached co-residency capacity
                if (coop_blocks < 0) {
                    int dev = 0; (void)hipGetDevice(&dev);
                    int sup = 0;
                    (void)hipDeviceGetAttribute(&sup, hipDeviceAttributeCooperativeLaunch, dev);
                    int ncu = 0;
                    (void)hipDeviceGetAttribute(&ncu, hipDeviceAttributeMultiprocessorCount, dev);
                    int maxb = 0;
                    (void)hipOccupancyMaxActiveBlocksPerMultiprocessor(
                        &maxb, (const void*)k_fused, 512, sc_lds);
                    coop_blocks = (sup != 0) ? maxb * ncu : 0;
                }
                if (coop_blocks >= NSUB) {
                    const float* xa = x;
                    const int* sa = src;
                    const int* da = dst;
                    float* oa = out;
                    int ne = n_edges, nn = n_nodes, nbv = nb, ck = chunk;
                    void* args[] = { &xa, &sa, &da, &cnt_p, &bin_p, &ovfb_p, &ovfn_p,
                                     &tick_p, &oa, &ne, &nn, &nbv, &ck };
                    hipError_t err = hipLaunchCooperativeKernel(
                        (const void*)k_fused, dim3(NSUB), dim3(512), args,
                        (unsigned)sc_lds, stream);
                    if (err == hipSuccess) return;
                }
            }
        }
        // ---- fallback: proven 2-kernel path ----
        const int ncand[3] = {512, 384, 256};
        for (int ci = 0; ci < 3; ++ci) {
            int nsub = ncand[ci];
            int chunk = (n_edges + nsub - 1) / nsub;
            size_t need = ((size_t)nsub * nb
                           + 512
                           + 2 * (size_t)nsub * OVFB
                           + (((size_t)nb * nsub) << CAPSH))
                          * sizeof(u32);
            if (need > ws_size) continue;

            u32* cnt  = (u32*)d_ws;
            u32* ovfn = cnt + (size_t)nsub * nb;
            u32* ovfb = ovfn + 512;
            u32* bin  = ovfb + 2 * (size_t)nsub * OVFB;

            k_scatter5<<<nsub, 512, sc_lds, stream>>>(src, dst, cnt, bin, ovfb, ovfn,
                                                      n_edges, nb, nsub, chunk);
            k_gather5<<<nb, 512, 0, stream>>>(x, cnt, bin, ovfb, ovfn, out,
                                              n_nodes, nb, nsub);
            return;
        }
    }

    // last-resort: atomic path
    mp_zero_kernel<<<(out_size + 255) / 256, 256, 0, stream>>>(out, out_size);
    int total_thr = n_edges * 8;
    mp_scatter_kernel<<<(total_thr + 255) / 256, 256, 0, stream>>>(x, src, dst, out, n_edges);
}